// Round 14
// baseline (3717.477 us; speedup 1.0000x reference)
//
#include <hip/hip_runtime.h>
#include <hip/hip_bf16.h>
#include <math.h>

static constexpr int V = 32000, B = 4, T = 1024, C = 1024, H = 16, NL = 8, HS = 64;
static constexpr int M = B * T; // 4096 rows of activations

typedef __bf16 bf16x8 __attribute__((ext_vector_type(8)));
typedef __bf16 bf16x4 __attribute__((ext_vector_type(4)));
typedef float f32x4 __attribute__((ext_vector_type(4)));

#define AS1 __attribute__((address_space(1)))
#define AS3 __attribute__((address_space(3)))

// ---------------------------------------------------------------- embed
__global__ void k_embed(const int* __restrict__ idx, const float* __restrict__ tok,
                        const float* __restrict__ pos, float* __restrict__ x) {
  int g = blockIdx.x * blockDim.x + threadIdx.x; // over M*C/4
  if (g >= M * C / 4) return;
  int c4 = g & 255;
  int bt = g >> 8;
  int t = bt & (T - 1);
  int row = idx[bt];
  float4 tv = *(const float4*)(tok + (size_t)row * C + c4 * 4);
  float4 pv = *(const float4*)(pos + (size_t)t * C + c4 * 4);
  float4 o;
  o.x = tv.x + pv.x; o.y = tv.y + pv.y; o.z = tv.z + pv.z; o.w = tv.w + pv.w;
  *(float4*)(x + (size_t)bt * C + c4 * 4) = o;
}

// ---------------------------------------------------------------- layernorm fp32 -> bf16
__global__ __launch_bounds__(256) void k_ln_bf(const float* __restrict__ x, const float* __restrict__ g,
                                               const float* __restrict__ b, __hip_bfloat16* __restrict__ y) {
  int row = blockIdx.x, tid = threadIdx.x;
  float4 v = ((const float4*)(x + (size_t)row * C))[tid];
  float s = v.x + v.y + v.z + v.w;
  float ss = v.x * v.x + v.y * v.y + v.z * v.z + v.w * v.w;
  for (int off = 32; off > 0; off >>= 1) {
    s += __shfl_down(s, off);
    ss += __shfl_down(ss, off);
  }
  __shared__ float sb[4], qb[4];
  int wid = tid >> 6;
  if ((tid & 63) == 0) { sb[wid] = s; qb[wid] = ss; }
  __syncthreads();
  float st = sb[0] + sb[1] + sb[2] + sb[3];
  float qt = qb[0] + qb[1] + qb[2] + qb[3];
  float mean = st * (1.0f / C);
  float var = qt * (1.0f / C) - mean * mean;
  float rstd = rsqrtf(var + 1e-5f);
  float4 gv = ((const float4*)g)[tid];
  float4 bv = ((const float4*)b)[tid];
  union { __hip_bfloat16 h[4]; ushort4 u; } pk;
  pk.h[0] = __float2bfloat16((v.x - mean) * rstd * gv.x + bv.x);
  pk.h[1] = __float2bfloat16((v.y - mean) * rstd * gv.y + bv.y);
  pk.h[2] = __float2bfloat16((v.z - mean) * rstd * gv.z + bv.z);
  pk.h[3] = __float2bfloat16((v.w - mean) * rstd * gv.w + bv.w);
  *(ushort4*)(y + (size_t)row * C + tid * 4) = pk.u;
}

// ---------------------------------------------------------------- transpose tile helper (device)
__device__ __forceinline__ void transp_block(const float* __restrict__ in, __hip_bfloat16* __restrict__ out,
                                             int K, int N, int bx, int by, float (*t)[65]) {
  int n0 = bx * 64, k0 = by * 64;
  int tx = threadIdx.x & 15, ty = threadIdx.x >> 4;
#pragma unroll
  for (int i = 0; i < 64; i += 16) {
    float4 v = *(const float4*)(in + (size_t)(k0 + ty + i) * N + n0 + tx * 4);
    t[ty + i][tx * 4 + 0] = v.x;
    t[ty + i][tx * 4 + 1] = v.y;
    t[ty + i][tx * 4 + 2] = v.z;
    t[ty + i][tx * 4 + 3] = v.w;
  }
  __syncthreads();
#pragma unroll
  for (int i = 0; i < 64; i += 16) {
    int n = ty + i;
    union { __hip_bfloat16 h[4]; ushort4 u; } pk;
#pragma unroll
    for (int j = 0; j < 4; ++j) pk.h[j] = __float2bfloat16(t[tx * 4 + j][n]);
    *(ushort4*)(out + (size_t)(n0 + n) * K + k0 + tx * 4) = pk.u;
  }
}

// ---------------------------------------------------------------- standalone transpose (head weight)
__global__ __launch_bounds__(256) void k_transp(const float* __restrict__ in, __hip_bfloat16* __restrict__ out,
                                                int K, int N) {
  __shared__ float t[64][65];
  transp_block(in, out, K, N, blockIdx.x, blockIdx.y, t);
}

// ---------------------------------------------------------------- merged per-layer weight prep
// bid 0..767: qkv pack; 768..1023: Pm^T; 1024..2047: Ph conv; 2048..3071: W1^T; 3072..4095: W2^T
__global__ __launch_bounds__(256) void k_prep(const float* __restrict__ Wq, const float* __restrict__ Wk,
                                              const float* __restrict__ Wv, const float* __restrict__ Pm,
                                              const float* __restrict__ Ph, const float* __restrict__ W1,
                                              const float* __restrict__ W2,
                                              __hip_bfloat16* __restrict__ qkvw, __hip_bfloat16* __restrict__ pmT,
                                              __hip_bfloat16* __restrict__ phB, __hip_bfloat16* __restrict__ w1T,
                                              __hip_bfloat16* __restrict__ w2T) {
  __shared__ float tls[64][65];
  int bid = blockIdx.x;
  if (bid < 768) {
    int bx = bid & 15, z = bid >> 4;
    int sel = z >> 4, h = z & 15;
    const float* W = sel == 0 ? Wq : (sel == 1 ? Wk : Wv);
    const float* in = W + (size_t)h * C * HS;
    __hip_bfloat16* o = qkvw + ((size_t)sel * 1024 + h * 64) * C;
    int k0 = bx * 64;
    int tx = threadIdx.x & 15, ty = threadIdx.x >> 4;
#pragma unroll
    for (int i = 0; i < 64; i += 16) {
      float4 v = *(const float4*)(in + (size_t)(k0 + ty + i) * HS + tx * 4);
      tls[ty + i][tx * 4 + 0] = v.x;
      tls[ty + i][tx * 4 + 1] = v.y;
      tls[ty + i][tx * 4 + 2] = v.z;
      tls[ty + i][tx * 4 + 3] = v.w;
    }
    __syncthreads();
#pragma unroll
    for (int i = 0; i < 64; i += 16) {
      int n = ty + i;
      union { __hip_bfloat16 h4[4]; ushort4 u; } pk;
#pragma unroll
      for (int j = 0; j < 4; ++j) pk.h4[j] = __float2bfloat16(tls[tx * 4 + j][n]);
      *(ushort4*)(o + (size_t)n * C + k0 + tx * 4) = pk.u;
    }
  } else if (bid < 1024) {
    int r = bid - 768;
    transp_block(Pm, pmT, C, C, r & 15, r >> 4, tls);
  } else if (bid < 2048) {
    int g = (bid - 1024) * 256 + threadIdx.x;  // over C*C/4
    float4 v = ((const float4*)Ph)[g];
    union { __hip_bfloat16 h[4]; ushort4 u; } pk;
    pk.h[0] = __float2bfloat16(v.x);
    pk.h[1] = __float2bfloat16(v.y);
    pk.h[2] = __float2bfloat16(v.z);
    pk.h[3] = __float2bfloat16(v.w);
    ((ushort4*)phB)[g] = pk.u;
  } else if (bid < 3072) {
    int r = bid - 2048;
    transp_block(W1, w1T, C, 4 * C, r & 63, r >> 6, tls);
  } else {
    int r = bid - 3072;
    transp_block(W2, w2T, 4 * C, C, r & 15, r >> 4, tls);
  }
}

// ---------------------------------------------------------------- merged bias: bc = (sum_h Phb[h]) @ Pm + Pm_b
__global__ __launch_bounds__(256) void k_biasc(const float* __restrict__ phb, const float* __restrict__ Pm,
                                               const float* __restrict__ Pmb, float* __restrict__ bc) {
  __shared__ float bs[1024];
  __shared__ float red[4][64];
  int tid = threadIdx.x;
#pragma unroll
  for (int q = 0; q < 4; ++q) {
    int c = tid * 4 + q;
    float s = 0.0f;
    for (int h = 0; h < H; ++h) s += phb[(size_t)h * C + c];
    bs[c] = s;
  }
  __syncthreads();
  int c = blockIdx.x * 64 + (tid & 63);
  int part = tid >> 6;
  float s = 0.0f;
  for (int j = part * 256; j < part * 256 + 256; ++j) s += bs[j] * Pm[(size_t)j * C + c];
  red[part][tid & 63] = s;
  __syncthreads();
  if (tid < 64)
    bc[blockIdx.x * 64 + tid] = Pmb[blockIdx.x * 64 + tid] + red[0][tid] + red[1][tid] + red[2][tid] + red[3][tid];
}

// ---------------------------------------------------------------- bf16 MFMA GEMM (m97 structure, 128x128, BK=32)
template <int BIAS, int GELU, int RES, int OUTBF>
__global__ __launch_bounds__(256) void k_gemm_bf(const __hip_bfloat16* __restrict__ A,
                                                 const __hip_bfloat16* __restrict__ Bt,
                                                 void* Cout, const float* __restrict__ bias,
                                                 const float* res, int N, int K) {
  __shared__ __align__(16) __hip_bfloat16 As[128 * 32];
  __shared__ __align__(16) __hip_bfloat16 Bs[128 * 32];
  int bm = blockIdx.y * 128, bn = blockIdx.x * 128;
  int tid = threadIdx.x;
  int w = tid >> 6, l = tid & 63;
  int wr = (w >> 1) * 64, wc = (w & 1) * 64;
  int lr = l >> 2;
  int lk = (l & 3) * 8;
  int fr = l & 15;
  int fk = (l >> 4) * 8;
  const __hip_bfloat16* Ag = A + (size_t)bm * K;
  const __hip_bfloat16* Bg = Bt + (size_t)bn * K;
  f32x4 acc[4][4];
#pragma unroll
  for (int m = 0; m < 4; ++m)
#pragma unroll
    for (int n = 0; n < 4; ++n) acc[m][n] = (f32x4){0.f, 0.f, 0.f, 0.f};

  for (int k0 = 0; k0 < K; k0 += 32) {
    __syncthreads();
#pragma unroll
    for (int i = 0; i < 2; ++i) {
      int seg = w * 2 + i;
      int r = seg * 16 + lr;
      __builtin_amdgcn_global_load_lds((const AS1 void*)(Ag + (size_t)r * K + k0 + lk),
                                       (AS3 void*)(As + seg * 512), 16, 0, 0);
      __builtin_amdgcn_global_load_lds((const AS1 void*)(Bg + (size_t)r * K + k0 + lk),
                                       (AS3 void*)(Bs + seg * 512), 16, 0, 0);
    }
    __syncthreads();
    bf16x8 af[4], bfr[4];
#pragma unroll
    for (int m = 0; m < 4; ++m) af[m] = *(const bf16x8*)(As + ((size_t)(wr + m * 16 + fr)) * 32 + fk);
#pragma unroll
    for (int n = 0; n < 4; ++n) bfr[n] = *(const bf16x8*)(Bs + ((size_t)(wc + n * 16 + fr)) * 32 + fk);
#pragma unroll
    for (int m = 0; m < 4; ++m)
#pragma unroll
      for (int n = 0; n < 4; ++n)
        acc[m][n] = __builtin_amdgcn_mfma_f32_16x16x32_bf16(af[m], bfr[n], acc[m][n], 0, 0, 0);
  }
  int crow0 = (l >> 4) * 4;
  int ccol = l & 15;
#pragma unroll
  for (int m = 0; m < 4; ++m) {
    int row = bm + wr + m * 16 + crow0;
#pragma unroll
    for (int n = 0; n < 4; ++n) {
      int col = bn + wc + n * 16 + ccol;
      float bv = BIAS ? bias[col] : 0.0f;
#pragma unroll
      for (int r = 0; r < 4; ++r) {
        float v = acc[m][n][r] + bv;
        if (GELU) v = 0.5f * v * (1.0f + erff(v * 0.70710678118f));
        if (RES) v += res[(size_t)(row + r) * N + col];
        if (OUTBF)
          ((__hip_bfloat16*)Cout)[(size_t)(row + r) * N + col] = __float2bfloat16(v);
        else
          ((float*)Cout)[(size_t)(row + r) * N + col] = v;
      }
    }
  }
}

// ---------------------------------------------------------------- 256x256 pipelined MFMA GEMM (8 waves, BK=32)
// Proven R13 version (head ~355us, at the ~3 TB/s L2-miss-path floor for its tile
// geometry -- kept as control; see R13 post-mortem).
template <int BIAS, int GELU, int RES, int OUTBF>
__global__ __launch_bounds__(512, 2) void k_gemm256(const __hip_bfloat16* __restrict__ Ah,
                                                    const __hip_bfloat16* __restrict__ Bth,
                                                    void* Cout, const float* __restrict__ bias,
                                                    const float* res, int N, int K) {
  __shared__ __align__(16) __bf16 As[4][256 * 32];
  __shared__ __align__(16) __bf16 Bs[4][256 * 32];
  const __bf16* A = (const __bf16*)Ah;
  const __bf16* Bt = (const __bf16*)Bth;
  const int nx = N >> 8;
  const int bid = blockIdx.x;
  const int sw = ((bid & 7) * ((int)gridDim.x >> 3)) + (bid >> 3);  // XCD-chunk swizzle
  const int bn = (sw % nx) << 8;
  const int bm = (sw / nx) << 8;
  const int tid = threadIdx.x, w = tid >> 6, l = tid & 63;
  const int wm = w >> 2, wn = w & 3;
  const int fr = l & 15, fg = l >> 4;
  const int srow = w * 32 + (l >> 2);  // + jj*16
  const int scole = ((((l & 3) << 4) ^ ((l & 8) << 2) ^ (l & 16)) >> 1);
  const __bf16* Ag = A + (size_t)(bm + srow) * K + scole;
  const __bf16* Bg = Bt + (size_t)(bn + srow) * K + scole;
  const int arow = wm * 128 + fr;  // + mg*16
  const int brow = wn * 64 + fr;   // + ng*16
  const int koff = (((fg * 16) ^ (((fr & 2) << 4) | ((fr & 4) << 2))) >> 1);  // elements

  f32x4 acc[8][4];
#pragma unroll
  for (int m = 0; m < 8; ++m)
#pragma unroll
    for (int n = 0; n < 4; ++n) acc[m][n] = (f32x4){0.f, 0.f, 0.f, 0.f};

  auto stage = [&](int bufi, int tt) {
    size_t kb = (size_t)tt * 32;
#pragma unroll
    for (int jj = 0; jj < 2; ++jj) {
      __builtin_amdgcn_global_load_lds((const AS1 void*)(Ag + (size_t)jj * 16 * K + kb),
                                       (AS3 void*)(&As[bufi][(w * 32 + jj * 16) * 32]), 16, 0, 0);
      __builtin_amdgcn_global_load_lds((const AS1 void*)(Bg + (size_t)jj * 16 * K + kb),
                                       (AS3 void*)(&Bs[bufi][(w * 32 + jj * 16) * 32]), 16, 0, 0);
    }
  };

  bf16x8 fa[2][8], fb[2][4];

#define READF(SET, BI)                                                              \
  {                                                                                 \
    const int bi_ = (BI);                                                           \
    _Pragma("unroll") for (int mg = 0; mg < 8; ++mg)                                \
        fa[SET][mg] = *(const bf16x8*)(&As[bi_][(arow + mg * 16) * 32 + koff]);     \
    _Pragma("unroll") for (int ng = 0; ng < 4; ++ng)                                \
        fb[SET][ng] = *(const bf16x8*)(&Bs[bi_][(brow + ng * 16) * 32 + koff]);     \
  }

#define MFMAS(SET)                                                                  \
  _Pragma("unroll") for (int mg = 0; mg < 8; ++mg)                                  \
      _Pragma("unroll") for (int ng = 0; ng < 4; ++ng)                              \
          acc[mg][ng] =                                                             \
              __builtin_amdgcn_mfma_f32_16x16x32_bf16(fa[SET][mg], fb[SET][ng], acc[mg][ng], 0, 0, 0);

#define GITER(T, CUR, NXT)                                                          \
  {                                                                                 \
    const int t_ = (T);                                                             \
    asm volatile("s_waitcnt lgkmcnt(0)" ::: "memory");                              \
    if (t_ + 2 < NT)                                                                \
      asm volatile("s_waitcnt vmcnt(4)" ::: "memory");                              \
    else                                                                            \
      asm volatile("s_waitcnt vmcnt(0)" ::: "memory");                              \
    __builtin_amdgcn_sched_barrier(0);                                              \
    __builtin_amdgcn_s_barrier();                                                   \
    __builtin_amdgcn_sched_barrier(0);                                              \
    if (t_ + 1 < NT) READF(NXT, (t_ + 1) & 3);                                      \
    if (t_ + 3 < NT) stage((t_ + 3) & 3, t_ + 3);                                   \
    __builtin_amdgcn_s_setprio(1);                                                  \
    MFMAS(CUR);                                                                     \
    __builtin_amdgcn_s_setprio(0);                                                  \
  }

  const int NT = K >> 5;
  stage(0, 0);
  stage(1, 1);
  stage(2, 2);
  asm volatile("s_waitcnt vmcnt(8)" ::: "memory");
  __builtin_amdgcn_sched_barrier(0);
  __builtin_amdgcn_s_barrier();
  __builtin_amdgcn_sched_barrier(0);
  READF(0, 0);

  for (int t = 0; t < NT; t += 2) {
    GITER(t, 0, 1);
    GITER(t + 1, 1, 0);
  }
#undef READF
#undef MFMAS
#undef GITER

#pragma unroll
  for (int mg = 0; mg < 8; ++mg) {
    int row = bm + wm * 128 + mg * 16 + fg * 4;
#pragma unroll
    for (int n = 0; n < 4; ++n) {
      int col = bn + wn * 64 + n * 16 + fr;
      float bvx = BIAS ? bias[col] : 0.0f;
#pragma unroll
      for (int r = 0; r < 4; ++r) {
        float v = acc[mg][n][r] + bvx;
        if (GELU) v = 0.5f * v * (1.0f + erff(v * 0.70710678118f));
        if (RES) v += res[(size_t)(row + r) * N + col];
        if (OUTBF)
          ((__hip_bfloat16*)Cout)[(size_t)(row + r) * N + col] = __float2bfloat16(v);
        else
          ((float*)Cout)[(size_t)(row + r) * N + col] = v;
      }
    }
  }
}

// ---------------------------------------------------------------- MFMA flash attention
// CHANGE (R14): V stored TRANSPOSED in LDS (Vt[d][kv], 40-el rows = 80B, 16B-aligned)
// so each PV B-fragment is ONE ds_read_b128 instead of 8 scalar ds_read_u16
// (disasm red-flag #2). Staging scatters 8 ds_write_b16/thread (overlapped, write-side).
__global__ __launch_bounds__(256) void k_attn(const __hip_bfloat16* __restrict__ qkvh,
                                              __hip_bfloat16* __restrict__ o) {
  const __bf16* qkv = (const __bf16*)qkvh;
  int qi = blockIdx.x;
  int bh = blockIdx.y;
  int b = bh >> 4, h = bh & 15;
  int tid = threadIdx.x;
  int w = tid >> 6, l = tid & 63;
  int fr = l & 15, fg = l >> 4;
  int qw = qi * 64 + w * 16;

  __shared__ __align__(16) __bf16 Ks[32][72];
  __shared__ __align__(16) __bf16 Vt[64][40];  // V transposed: [d][kv]
  __shared__ __align__(16) __bf16 Ps[4][16][40];

  const size_t bT = (size_t)b * T;
  bf16x8 a_q[2];
  {
    const __bf16* qp = qkv + (bT + qw + fr) * 3072 + h * 64 + fg * 8;
    a_q[0] = *(const bf16x8*)qp;
    a_q[1] = *(const bf16x8*)(qp + 32);
  }
  f32x4 acc_o[4];
#pragma unroll
  for (int n = 0; n < 4; ++n) acc_o[n] = (f32x4){0.f, 0.f, 0.f, 0.f};
  float mrow[4] = {-1e30f, -1e30f, -1e30f, -1e30f};
  float lrow[4] = {0.f, 0.f, 0.f, 0.f};

  int sr = tid >> 3;
  int sc = (tid & 7) * 8;
  int ntile = (qi + 1) * 2;
  for (int t = 0; t < ntile; ++t) {
    int kv0 = t * 32;
    __syncthreads();
    {
      const __bf16* kp = qkv + (bT + kv0 + sr) * 3072 + 1024 + h * 64 + sc;
      bf16x8 k8 = *(const bf16x8*)kp;
      bf16x8 v8 = *(const bf16x8*)(kp + 1024);
      *(bf16x8*)&Ks[sr][sc] = k8;
#pragma unroll
      for (int j = 0; j < 8; ++j) Vt[sc + j][sr] = v8[j];
    }
    __syncthreads();
    if (kv0 > qw + 15) continue;

    f32x4 s0 = (f32x4){0.f, 0.f, 0.f, 0.f}, s1 = s0;
    s0 = __builtin_amdgcn_mfma_f32_16x16x32_bf16(a_q[0], *(const bf16x8*)&Ks[fr][fg * 8], s0, 0, 0, 0);
    s0 = __builtin_amdgcn_mfma_f32_16x16x32_bf16(a_q[1], *(const bf16x8*)&Ks[fr][32 + fg * 8], s0, 0, 0, 0);
    s1 = __builtin_amdgcn_mfma_f32_16x16x32_bf16(a_q[0], *(const bf16x8*)&Ks[16 + fr][fg * 8], s1, 0, 0, 0);
    s1 = __builtin_amdgcn_mfma_f32_16x16x32_bf16(a_q[1], *(const bf16x8*)&Ks[16 + fr][32 + fg * 8], s1, 0, 0, 0);

    int qrow = qw + fg * 4;
#pragma unroll
    for (int r = 0; r < 4; ++r) { s0[r] *= 0.03125f; s1[r] *= 0.03125f; }
    if (kv0 + 31 > qw) {
#pragma unroll
      for (int r = 0; r < 4; ++r) {
        if (kv0 + fr > qrow + r) s0[r] = -1e30f;
        if (kv0 + 16 + fr > qrow + r) s1[r] = -1e30f;
      }
    }
    float tm[4], psum[4], alpha[4];
#pragma unroll
    for (int r = 0; r < 4; ++r) tm[r] = fmaxf(s0[r], s1[r]);
#pragma unroll
    for (int off = 1; off < 16; off <<= 1)
#pragma unroll
      for (int r = 0; r < 4; ++r) tm[r] = fmaxf(tm[r], __shfl_xor(tm[r], off));
#pragma unroll
    for (int r = 0; r < 4; ++r) {
      float mnew = fmaxf(mrow[r], tm[r]);
      alpha[r] = __expf(mrow[r] - mnew);
      mrow[r] = mnew;
      float p0 = __expf(s0[r] - mnew);
      float p1 = __expf(s1[r] - mnew);
      s0[r] = p0; s1[r] = p1;
      psum[r] = p0 + p1;
    }
#pragma unroll
    for (int off = 1; off < 16; off <<= 1)
#pragma unroll
      for (int r = 0; r < 4; ++r) psum[r] += __shfl_xor(psum[r], off);
#pragma unroll
    for (int r = 0; r < 4; ++r) lrow[r] = lrow[r] * alpha[r] + psum[r];
#pragma unroll
    for (int n = 0; n < 4; ++n)
#pragma unroll
      for (int r = 0; r < 4; ++r) acc_o[n][r] *= alpha[r];

#pragma unroll
    for (int r = 0; r < 4; ++r) {
      Ps[w][fg * 4 + r][fr] = (__bf16)s0[r];
      Ps[w][fg * 4 + r][16 + fr] = (__bf16)s1[r];
    }
    bf16x8 a_p = *(const bf16x8*)&Ps[w][fr][fg * 8];
    // PV: B-frag col=d (n*16+fr), k=kv (fg*8+j) -> one b128 from Vt per fragment
#pragma unroll
    for (int n = 0; n < 4; ++n) {
      bf16x8 bvv = *(const bf16x8*)&Vt[n * 16 + fr][fg * 8];
      acc_o[n] = __builtin_amdgcn_mfma_f32_16x16x32_bf16(a_p, bvv, acc_o[n], 0, 0, 0);
    }
  }
  float inv[4];
#pragma unroll
  for (int r = 0; r < 4; ++r) inv[r] = 1.0f / lrow[r];
  __bf16* ob = (__bf16*)o;
#pragma unroll
  for (int n = 0; n < 4; ++n)
#pragma unroll
    for (int r = 0; r < 4; ++r)
      ob[(bT + qw + fg * 4 + r) * 1024 + h * 64 + n * 16 + fr] = (__bf16)(acc_o[n][r] * inv[r]);
}

// ---------------------------------------------------------------- launch
extern "C" void kernel_launch(void* const* d_in, const int* in_sizes, int n_in,
                              void* d_out, int out_size, void* d_ws, size_t ws_size,
                              hipStream_t stream) {
  const int* idx = (const int*)d_in[0];
  const float* tok = (const float*)d_in[1];
  const float* pos = (const float*)d_in[2];
  const float* Wq = (const float*)d_in[3];
  const float* Wk = (const float*)d_in[4];
  const float* Wv = (const float*)d_in[5];
  const float* Phw = (const float*)d_in[6];
  const float* Phb = (const float*)d_in[7];
  const float* Pmw = (const float*)d_in[8];
  const float* Pmb = (const float*)d_in[9];
  const float* ln1g = (const float*)d_in[10];
  const float* ln1b = (const float*)d_in[11];
  const float* ln2g = (const float*)d_in[12];
  const float* ln2b = (const float*)d_in[13];
  const float* W1 = (const float*)d_in[14];
  const float* b1 = (const float*)d_in[15];
  const float* W2 = (const float*)d_in[16];
  const float* b2 = (const float*)d_in[17];
  const float* lnfg = (const float*)d_in[18];
  const float* lnfb = (const float*)d_in[19];
  const float* headw = (const float*)d_in[20];
  const float* headb = (const float*)d_in[21];
  float* out = (float*)d_out;

  // Workspace (~116 MB): x | bc | [qkvb ob hb = 64MB head-alias region] | xn | weights
  char* p = (char*)d_ws;
  float* x = (float*)p;                        p += (size_t)M * C * 4;
  float* bcv = (float*)p;                      p += 4096;
  char* layer_region = p;
  __hip_bfloat16* qkvb = (__hip_bfloat16*)p;   p += (size_t)M * 3072 * 2;
  __hip_bfloat16* ob = (__hip_bfloat16*)p;     p += (size_t)M * C * 2;
  __hip_bfloat16* hb = (__hip_bfloat16*)p;     p += (size_t)M * 4 * C * 2;
  __hip_bfloat16* xn = (__hip_bfloat16*)p;     p += (size_t)M * C * 2;
  __hip_bfloat16* qkvw = (__hip_bfloat16*)p;   p += (size_t)3 * C * C * 2;
  __hip_bfloat16* pmT = (__hip_bfloat16*)p;    p += (size_t)C * C * 2;
  __hip_bfloat16* phB = (__hip_bfloat16*)p;    p += (size_t)C * C * 2;
  __hip_bfloat16* wcombT = (__hip_bfloat16*)p; p += (size_t)C * C * 2;
  __hip_bfloat16* w1T = (__hip_bfloat16*)p;    p += (size_t)4 * C * C * 2;
  __hip_bfloat16* w2T = (__hip_bfloat16*)p;    p += (size_t)4 * C * C * 2;
  __hip_bfloat16* wt_head = (__hip_bfloat16*)layer_region;  // [V,C] bf16 = 64MB alias

  k_embed<<<(M * C / 4 + 255) / 256, 256, 0, stream>>>(idx, tok, pos, x);

  for (int l = 0; l < NL; ++l) {
    // ln1 -> xn (bf16)
    k_ln_bf<<<M, 256, 0, stream>>>(x, ln1g + (size_t)l * C, ln1b + (size_t)l * C, xn);
    // all weight prep in one launch
    k_prep<<<4096, 256, 0, stream>>>(Wq + (size_t)l * H * C * HS, Wk + (size_t)l * H * C * HS,
                                     Wv + (size_t)l * H * C * HS, Pmw + (size_t)l * C * C,
                                     Phw + (size_t)l * H * HS * C, W1 + (size_t)l * C * 4 * C,
                                     W2 + (size_t)l * 4 * C * C, qkvw, pmT, phB, w1T, w2T);
    // qkv = xn @ qkvw^T -> bf16 [M,3072]
    k_gemm256<0, 0, 0, 1><<<(3072 / 256) * (M / 256), 512, 0, stream>>>(xn, qkvw, qkvb, nullptr, nullptr, 3072, C);
    // attention -> ob (bf16)
    k_attn<<<dim3(T / 64, B * H), 256, 0, stream>>>(qkvb, ob);
    // combined bias + fused Ph*Pm weight
    k_biasc<<<16, 256, 0, stream>>>(Phb + (size_t)l * H * C, Pmw + (size_t)l * C * C, Pmb + (size_t)l * C, bcv);
    k_gemm_bf<0, 0, 0, 1><<<dim3(C / 128, C / 128), 256, 0, stream>>>(pmT, phB, wcombT, nullptr, nullptr, C, C);
    // x = x + ob @ wcombT^T + bc
    k_gemm_bf<1, 0, 1, 0><<<dim3(C / 128, M / 128), 256, 0, stream>>>(ob, wcombT, x, bcv, x, C, C);
    // ln2 -> xn
    k_ln_bf<<<M, 256, 0, stream>>>(x, ln2g + (size_t)l * C, ln2b + (size_t)l * C, xn);
    // h = gelu(xn @ W1 + b1)
    k_gemm256<1, 1, 0, 1><<<(4 * C / 256) * (M / 256), 512, 0, stream>>>(xn, w1T, hb, b1 + (size_t)l * 4 * C, nullptr, 4 * C, C);
    // x = x + h @ W2 + b2
    k_gemm_bf<1, 0, 1, 0><<<dim3(C / 128, M / 128), 256, 0, stream>>>(hb, w2T, x, b2 + (size_t)l * C, x, C, 4 * C);
  }

  // final LN + head
  k_ln_bf<<<M, 256, 0, stream>>>(x, lnfg, lnfb, xn);
  k_transp<<<dim3(500, 16), 256, 0, stream>>>(headw, wt_head, C, V);
  k_gemm256<1, 0, 0, 0><<<(V / 256) * (M / 256), 512, 0, stream>>>(xn, wt_head, out, headb, nullptr, V, C);
}

// Round 15
// 3621.575 us; speedup vs baseline: 1.0265x; 1.0265x over previous
//
#include <hip/hip_runtime.h>
#include <hip/hip_bf16.h>
#include <math.h>

static constexpr int V = 32000, B = 4, T = 1024, C = 1024, H = 16, NL = 8, HS = 64;
static constexpr int M = B * T; // 4096 rows of activations

typedef __bf16 bf16x8 __attribute__((ext_vector_type(8)));
typedef __bf16 bf16x4 __attribute__((ext_vector_type(4)));
typedef float f32x4 __attribute__((ext_vector_type(4)));

#define AS1 __attribute__((address_space(1)))
#define AS3 __attribute__((address_space(3)))

// ---------------------------------------------------------------- embed
__global__ void k_embed(const int* __restrict__ idx, const float* __restrict__ tok,
                        const float* __restrict__ pos, float* __restrict__ x) {
  int g = blockIdx.x * blockDim.x + threadIdx.x; // over M*C/4
  if (g >= M * C / 4) return;
  int c4 = g & 255;
  int bt = g >> 8;
  int t = bt & (T - 1);
  int row = idx[bt];
  float4 tv = *(const float4*)(tok + (size_t)row * C + c4 * 4);
  float4 pv = *(const float4*)(pos + (size_t)t * C + c4 * 4);
  float4 o;
  o.x = tv.x + pv.x; o.y = tv.y + pv.y; o.z = tv.z + pv.z; o.w = tv.w + pv.w;
  *(float4*)(x + (size_t)bt * C + c4 * 4) = o;
}

// ---------------------------------------------------------------- layernorm fp32 -> bf16
__global__ __launch_bounds__(256) void k_ln_bf(const float* __restrict__ x, const float* __restrict__ g,
                                               const float* __restrict__ b, __hip_bfloat16* __restrict__ y) {
  int row = blockIdx.x, tid = threadIdx.x;
  float4 v = ((const float4*)(x + (size_t)row * C))[tid];
  float s = v.x + v.y + v.z + v.w;
  float ss = v.x * v.x + v.y * v.y + v.z * v.z + v.w * v.w;
  for (int off = 32; off > 0; off >>= 1) {
    s += __shfl_down(s, off);
    ss += __shfl_down(ss, off);
  }
  __shared__ float sb[4], qb[4];
  int wid = tid >> 6;
  if ((tid & 63) == 0) { sb[wid] = s; qb[wid] = ss; }
  __syncthreads();
  float st = sb[0] + sb[1] + sb[2] + sb[3];
  float qt = qb[0] + qb[1] + qb[2] + qb[3];
  float mean = st * (1.0f / C);
  float var = qt * (1.0f / C) - mean * mean;
  float rstd = rsqrtf(var + 1e-5f);
  float4 gv = ((const float4*)g)[tid];
  float4 bv = ((const float4*)b)[tid];
  union { __hip_bfloat16 h[4]; ushort4 u; } pk;
  pk.h[0] = __float2bfloat16((v.x - mean) * rstd * gv.x + bv.x);
  pk.h[1] = __float2bfloat16((v.y - mean) * rstd * gv.y + bv.y);
  pk.h[2] = __float2bfloat16((v.z - mean) * rstd * gv.z + bv.z);
  pk.h[3] = __float2bfloat16((v.w - mean) * rstd * gv.w + bv.w);
  *(ushort4*)(y + (size_t)row * C + tid * 4) = pk.u;
}

// ---------------------------------------------------------------- transpose tile helper (device)
__device__ __forceinline__ void transp_block(const float* __restrict__ in, __hip_bfloat16* __restrict__ out,
                                             int K, int N, int bx, int by, float (*t)[65]) {
  int n0 = bx * 64, k0 = by * 64;
  int tx = threadIdx.x & 15, ty = threadIdx.x >> 4;
#pragma unroll
  for (int i = 0; i < 64; i += 16) {
    float4 v = *(const float4*)(in + (size_t)(k0 + ty + i) * N + n0 + tx * 4);
    t[ty + i][tx * 4 + 0] = v.x;
    t[ty + i][tx * 4 + 1] = v.y;
    t[ty + i][tx * 4 + 2] = v.z;
    t[ty + i][tx * 4 + 3] = v.w;
  }
  __syncthreads();
#pragma unroll
  for (int i = 0; i < 64; i += 16) {
    int n = ty + i;
    union { __hip_bfloat16 h[4]; ushort4 u; } pk;
#pragma unroll
    for (int j = 0; j < 4; ++j) pk.h[j] = __float2bfloat16(t[tx * 4 + j][n]);
    *(ushort4*)(out + (size_t)(n0 + n) * K + k0 + tx * 4) = pk.u;
  }
}

// ---------------------------------------------------------------- standalone transpose (head weight)
__global__ __launch_bounds__(256) void k_transp(const float* __restrict__ in, __hip_bfloat16* __restrict__ out,
                                                int K, int N) {
  __shared__ float t[64][65];
  transp_block(in, out, K, N, blockIdx.x, blockIdx.y, t);
}

// ---------------------------------------------------------------- merged per-layer weight prep
// bid 0..767: qkv pack; 768..1023: Pm^T; 1024..2047: Ph conv; 2048..3071: W1^T; 3072..4095: W2^T
__global__ __launch_bounds__(256) void k_prep(const float* __restrict__ Wq, const float* __restrict__ Wk,
                                              const float* __restrict__ Wv, const float* __restrict__ Pm,
                                              const float* __restrict__ Ph, const float* __restrict__ W1,
                                              const float* __restrict__ W2,
                                              __hip_bfloat16* __restrict__ qkvw, __hip_bfloat16* __restrict__ pmT,
                                              __hip_bfloat16* __restrict__ phB, __hip_bfloat16* __restrict__ w1T,
                                              __hip_bfloat16* __restrict__ w2T) {
  __shared__ float tls[64][65];
  int bid = blockIdx.x;
  if (bid < 768) {
    int bx = bid & 15, z = bid >> 4;
    int sel = z >> 4, h = z & 15;
    const float* W = sel == 0 ? Wq : (sel == 1 ? Wk : Wv);
    const float* in = W + (size_t)h * C * HS;
    __hip_bfloat16* o = qkvw + ((size_t)sel * 1024 + h * 64) * C;
    int k0 = bx * 64;
    int tx = threadIdx.x & 15, ty = threadIdx.x >> 4;
#pragma unroll
    for (int i = 0; i < 64; i += 16) {
      float4 v = *(const float4*)(in + (size_t)(k0 + ty + i) * HS + tx * 4);
      tls[ty + i][tx * 4 + 0] = v.x;
      tls[ty + i][tx * 4 + 1] = v.y;
      tls[ty + i][tx * 4 + 2] = v.z;
      tls[ty + i][tx * 4 + 3] = v.w;
    }
    __syncthreads();
#pragma unroll
    for (int i = 0; i < 64; i += 16) {
      int n = ty + i;
      union { __hip_bfloat16 h4[4]; ushort4 u; } pk;
#pragma unroll
      for (int j = 0; j < 4; ++j) pk.h4[j] = __float2bfloat16(tls[tx * 4 + j][n]);
      *(ushort4*)(o + (size_t)n * C + k0 + tx * 4) = pk.u;
    }
  } else if (bid < 1024) {
    int r = bid - 768;
    transp_block(Pm, pmT, C, C, r & 15, r >> 4, tls);
  } else if (bid < 2048) {
    int g = (bid - 1024) * 256 + threadIdx.x;  // over C*C/4
    float4 v = ((const float4*)Ph)[g];
    union { __hip_bfloat16 h[4]; ushort4 u; } pk;
    pk.h[0] = __float2bfloat16(v.x);
    pk.h[1] = __float2bfloat16(v.y);
    pk.h[2] = __float2bfloat16(v.z);
    pk.h[3] = __float2bfloat16(v.w);
    ((ushort4*)phB)[g] = pk.u;
  } else if (bid < 3072) {
    int r = bid - 2048;
    transp_block(W1, w1T, C, 4 * C, r & 63, r >> 6, tls);
  } else {
    int r = bid - 3072;
    transp_block(W2, w2T, 4 * C, C, r & 15, r >> 4, tls);
  }
}

// ---------------------------------------------------------------- merged bias: bc = (sum_h Phb[h]) @ Pm + Pm_b
__global__ __launch_bounds__(256) void k_biasc(const float* __restrict__ phb, const float* __restrict__ Pm,
                                               const float* __restrict__ Pmb, float* __restrict__ bc) {
  __shared__ float bs[1024];
  __shared__ float red[4][64];
  int tid = threadIdx.x;
#pragma unroll
  for (int q = 0; q < 4; ++q) {
    int c = tid * 4 + q;
    float s = 0.0f;
    for (int h = 0; h < H; ++h) s += phb[(size_t)h * C + c];
    bs[c] = s;
  }
  __syncthreads();
  int c = blockIdx.x * 64 + (tid & 63);
  int part = tid >> 6;
  float s = 0.0f;
  for (int j = part * 256; j < part * 256 + 256; ++j) s += bs[j] * Pm[(size_t)j * C + c];
  red[part][tid & 63] = s;
  __syncthreads();
  if (tid < 64)
    bc[blockIdx.x * 64 + tid] = Pmb[blockIdx.x * 64 + tid] + red[0][tid] + red[1][tid] + red[2][tid] + red[3][tid];
}

// ---------------------------------------------------------------- bf16 MFMA GEMM (m97 structure, 128x128, BK=32)
template <int BIAS, int GELU, int RES, int OUTBF>
__global__ __launch_bounds__(256) void k_gemm_bf(const __hip_bfloat16* __restrict__ A,
                                                 const __hip_bfloat16* __restrict__ Bt,
                                                 void* Cout, const float* __restrict__ bias,
                                                 const float* res, int N, int K) {
  __shared__ __align__(16) __hip_bfloat16 As[128 * 32];
  __shared__ __align__(16) __hip_bfloat16 Bs[128 * 32];
  int bm = blockIdx.y * 128, bn = blockIdx.x * 128;
  int tid = threadIdx.x;
  int w = tid >> 6, l = tid & 63;
  int wr = (w >> 1) * 64, wc = (w & 1) * 64;
  int lr = l >> 2;
  int lk = (l & 3) * 8;
  int fr = l & 15;
  int fk = (l >> 4) * 8;
  const __hip_bfloat16* Ag = A + (size_t)bm * K;
  const __hip_bfloat16* Bg = Bt + (size_t)bn * K;
  f32x4 acc[4][4];
#pragma unroll
  for (int m = 0; m < 4; ++m)
#pragma unroll
    for (int n = 0; n < 4; ++n) acc[m][n] = (f32x4){0.f, 0.f, 0.f, 0.f};

  for (int k0 = 0; k0 < K; k0 += 32) {
    __syncthreads();
#pragma unroll
    for (int i = 0; i < 2; ++i) {
      int seg = w * 2 + i;
      int r = seg * 16 + lr;
      __builtin_amdgcn_global_load_lds((const AS1 void*)(Ag + (size_t)r * K + k0 + lk),
                                       (AS3 void*)(As + seg * 512), 16, 0, 0);
      __builtin_amdgcn_global_load_lds((const AS1 void*)(Bg + (size_t)r * K + k0 + lk),
                                       (AS3 void*)(Bs + seg * 512), 16, 0, 0);
    }
    __syncthreads();
    bf16x8 af[4], bfr[4];
#pragma unroll
    for (int m = 0; m < 4; ++m) af[m] = *(const bf16x8*)(As + ((size_t)(wr + m * 16 + fr)) * 32 + fk);
#pragma unroll
    for (int n = 0; n < 4; ++n) bfr[n] = *(const bf16x8*)(Bs + ((size_t)(wc + n * 16 + fr)) * 32 + fk);
#pragma unroll
    for (int m = 0; m < 4; ++m)
#pragma unroll
      for (int n = 0; n < 4; ++n)
        acc[m][n] = __builtin_amdgcn_mfma_f32_16x16x32_bf16(af[m], bfr[n], acc[m][n], 0, 0, 0);
  }
  int crow0 = (l >> 4) * 4;
  int ccol = l & 15;
#pragma unroll
  for (int m = 0; m < 4; ++m) {
    int row = bm + wr + m * 16 + crow0;
#pragma unroll
    for (int n = 0; n < 4; ++n) {
      int col = bn + wc + n * 16 + ccol;
      float bv = BIAS ? bias[col] : 0.0f;
#pragma unroll
      for (int r = 0; r < 4; ++r) {
        float v = acc[m][n][r] + bv;
        if (GELU) v = 0.5f * v * (1.0f + erff(v * 0.70710678118f));
        if (RES) v += res[(size_t)(row + r) * N + col];
        if (OUTBF)
          ((__hip_bfloat16*)Cout)[(size_t)(row + r) * N + col] = __float2bfloat16(v);
        else
          ((float*)Cout)[(size_t)(row + r) * N + col] = v;
      }
    }
  }
}

// ---------------------------------------------------------------- 256x256 pipelined MFMA GEMM (8 waves, BK=32)
// Proven R13 version (head ~355us, at the ~3 TB/s L2-miss-path floor -- control).
template <int BIAS, int GELU, int RES, int OUTBF>
__global__ __launch_bounds__(512, 2) void k_gemm256(const __hip_bfloat16* __restrict__ Ah,
                                                    const __hip_bfloat16* __restrict__ Bth,
                                                    void* Cout, const float* __restrict__ bias,
                                                    const float* res, int N, int K) {
  __shared__ __align__(16) __bf16 As[4][256 * 32];
  __shared__ __align__(16) __bf16 Bs[4][256 * 32];
  const __bf16* A = (const __bf16*)Ah;
  const __bf16* Bt = (const __bf16*)Bth;
  const int nx = N >> 8;
  const int bid = blockIdx.x;
  const int sw = ((bid & 7) * ((int)gridDim.x >> 3)) + (bid >> 3);  // XCD-chunk swizzle
  const int bn = (sw % nx) << 8;
  const int bm = (sw / nx) << 8;
  const int tid = threadIdx.x, w = tid >> 6, l = tid & 63;
  const int wm = w >> 2, wn = w & 3;
  const int fr = l & 15, fg = l >> 4;
  const int srow = w * 32 + (l >> 2);  // + jj*16
  const int scole = ((((l & 3) << 4) ^ ((l & 8) << 2) ^ (l & 16)) >> 1);
  const __bf16* Ag = A + (size_t)(bm + srow) * K + scole;
  const __bf16* Bg = Bt + (size_t)(bn + srow) * K + scole;
  const int arow = wm * 128 + fr;  // + mg*16
  const int brow = wn * 64 + fr;   // + ng*16
  const int koff = (((fg * 16) ^ (((fr & 2) << 4) | ((fr & 4) << 2))) >> 1);  // elements

  f32x4 acc[8][4];
#pragma unroll
  for (int m = 0; m < 8; ++m)
#pragma unroll
    for (int n = 0; n < 4; ++n) acc[m][n] = (f32x4){0.f, 0.f, 0.f, 0.f};

  auto stage = [&](int bufi, int tt) {
    size_t kb = (size_t)tt * 32;
#pragma unroll
    for (int jj = 0; jj < 2; ++jj) {
      __builtin_amdgcn_global_load_lds((const AS1 void*)(Ag + (size_t)jj * 16 * K + kb),
                                       (AS3 void*)(&As[bufi][(w * 32 + jj * 16) * 32]), 16, 0, 0);
      __builtin_amdgcn_global_load_lds((const AS1 void*)(Bg + (size_t)jj * 16 * K + kb),
                                       (AS3 void*)(&Bs[bufi][(w * 32 + jj * 16) * 32]), 16, 0, 0);
    }
  };

  bf16x8 fa[2][8], fb[2][4];

#define READF(SET, BI)                                                              \
  {                                                                                 \
    const int bi_ = (BI);                                                           \
    _Pragma("unroll") for (int mg = 0; mg < 8; ++mg)                                \
        fa[SET][mg] = *(const bf16x8*)(&As[bi_][(arow + mg * 16) * 32 + koff]);     \
    _Pragma("unroll") for (int ng = 0; ng < 4; ++ng)                                \
        fb[SET][ng] = *(const bf16x8*)(&Bs[bi_][(brow + ng * 16) * 32 + koff]);     \
  }

#define MFMAS(SET)                                                                  \
  _Pragma("unroll") for (int mg = 0; mg < 8; ++mg)                                  \
      _Pragma("unroll") for (int ng = 0; ng < 4; ++ng)                              \
          acc[mg][ng] =                                                             \
              __builtin_amdgcn_mfma_f32_16x16x32_bf16(fa[SET][mg], fb[SET][ng], acc[mg][ng], 0, 0, 0);

#define GITER(T, CUR, NXT)                                                          \
  {                                                                                 \
    const int t_ = (T);                                                             \
    asm volatile("s_waitcnt lgkmcnt(0)" ::: "memory");                              \
    if (t_ + 2 < NT)                                                                \
      asm volatile("s_waitcnt vmcnt(4)" ::: "memory");                              \
    else                                                                            \
      asm volatile("s_waitcnt vmcnt(0)" ::: "memory");                              \
    __builtin_amdgcn_sched_barrier(0);                                              \
    __builtin_amdgcn_s_barrier();                                                   \
    __builtin_amdgcn_sched_barrier(0);                                              \
    if (t_ + 1 < NT) READF(NXT, (t_ + 1) & 3);                                      \
    if (t_ + 3 < NT) stage((t_ + 3) & 3, t_ + 3);                                   \
    __builtin_amdgcn_s_setprio(1);                                                  \
    MFMAS(CUR);                                                                     \
    __builtin_amdgcn_s_setprio(0);                                                  \
  }

  const int NT = K >> 5;
  stage(0, 0);
  stage(1, 1);
  stage(2, 2);
  asm volatile("s_waitcnt vmcnt(8)" ::: "memory");
  __builtin_amdgcn_sched_barrier(0);
  __builtin_amdgcn_s_barrier();
  __builtin_amdgcn_sched_barrier(0);
  READF(0, 0);

  for (int t = 0; t < NT; t += 2) {
    GITER(t, 0, 1);
    GITER(t + 1, 1, 0);
  }
#undef READF
#undef MFMAS
#undef GITER

#pragma unroll
  for (int mg = 0; mg < 8; ++mg) {
    int row = bm + wm * 128 + mg * 16 + fg * 4;
#pragma unroll
    for (int n = 0; n < 4; ++n) {
      int col = bn + wn * 64 + n * 16 + fr;
      float bvx = BIAS ? bias[col] : 0.0f;
#pragma unroll
      for (int r = 0; r < 4; ++r) {
        float v = acc[mg][n][r] + bvx;
        if (GELU) v = 0.5f * v * (1.0f + erff(v * 0.70710678118f));
        if (RES) v += res[(size_t)(row + r) * N + col];
        if (OUTBF)
          ((__hip_bfloat16*)Cout)[(size_t)(row + r) * N + col] = __float2bfloat16(v);
        else
          ((float*)Cout)[(size_t)(row + r) * N + col] = v;
      }
    }
  }
}

// ---------------------------------------------------------------- MFMA flash attention
// R15: PV path reverted to proven R13 layout (row-major Vs). Two structural changes:
// (1) tail-first qi mapping (longest causal blocks launch first -> better packing);
// (2) async-stage split (T14): K/V global loads for tile t+1 issued into registers
//     BEFORE computing tile t; LDS write after the post-compute barrier. Same 2
//     barriers/tile, but HBM/L2 latency hides under compute.
__global__ __launch_bounds__(256) void k_attn(const __hip_bfloat16* __restrict__ qkvh,
                                              __hip_bfloat16* __restrict__ o) {
  const __bf16* qkv = (const __bf16*)qkvh;
  int qi = (int)gridDim.x - 1 - (int)blockIdx.x;  // tail-first
  int bh = blockIdx.y;
  int b = bh >> 4, h = bh & 15;
  int tid = threadIdx.x;
  int w = tid >> 6, l = tid & 63;
  int fr = l & 15, fg = l >> 4;
  int qw = qi * 64 + w * 16;

  __shared__ __align__(16) __bf16 Ks[2][32][72];
  __shared__ __align__(16) __bf16 Vs[2][32][76];
  __shared__ __align__(16) __bf16 Ps[4][16][40];

  const size_t bT = (size_t)b * T;
  bf16x8 a_q[2];
  {
    const __bf16* qp = qkv + (bT + qw + fr) * 3072 + h * 64 + fg * 8;
    a_q[0] = *(const bf16x8*)qp;
    a_q[1] = *(const bf16x8*)(qp + 32);
  }
  f32x4 acc_o[4];
#pragma unroll
  for (int n = 0; n < 4; ++n) acc_o[n] = (f32x4){0.f, 0.f, 0.f, 0.f};
  float mrow[4] = {-1e30f, -1e30f, -1e30f, -1e30f};
  float lrow[4] = {0.f, 0.f, 0.f, 0.f};

  int sr = tid >> 3;
  int sc = (tid & 7) * 8;
  int ntile = (qi + 1) * 2;
  const __bf16* kbase = qkv + (bT + sr) * 3072 + 1024 + h * 64 + sc;

  // prologue: load tile 0, write buf 0
  {
    bf16x8 k8 = *(const bf16x8*)kbase;
    bf16x8 v8 = *(const bf16x8*)(kbase + 1024);
    *(bf16x8*)&Ks[0][sr][sc] = k8;
    *(bf16x4*)&Vs[0][sr][sc] = __builtin_shufflevector(v8, v8, 0, 1, 2, 3);
    *(bf16x4*)&Vs[0][sr][sc + 4] = __builtin_shufflevector(v8, v8, 4, 5, 6, 7);
  }
  __syncthreads();

  for (int t = 0; t < ntile; ++t) {
    int kv0 = t * 32;
    int cur = t & 1;
    // issue next tile's global loads early (latency hides under compute)
    bf16x8 k8n, v8n;
    if (t + 1 < ntile) {
      const __bf16* kp = kbase + (size_t)(t + 1) * 32 * 3072;
      k8n = *(const bf16x8*)kp;
      v8n = *(const bf16x8*)(kp + 1024);
    }
    if (kv0 <= qw + 15) {  // compute (no barriers inside)
      f32x4 s0 = (f32x4){0.f, 0.f, 0.f, 0.f}, s1 = s0;
      s0 = __builtin_amdgcn_mfma_f32_16x16x32_bf16(a_q[0], *(const bf16x8*)&Ks[cur][fr][fg * 8], s0, 0, 0, 0);
      s0 = __builtin_amdgcn_mfma_f32_16x16x32_bf16(a_q[1], *(const bf16x8*)&Ks[cur][fr][32 + fg * 8], s0, 0, 0, 0);
      s1 = __builtin_amdgcn_mfma_f32_16x16x32_bf16(a_q[0], *(const bf16x8*)&Ks[cur][16 + fr][fg * 8], s1, 0, 0, 0);
      s1 = __builtin_amdgcn_mfma_f32_16x16x32_bf16(a_q[1], *(const bf16x8*)&Ks[cur][16 + fr][32 + fg * 8], s1, 0, 0, 0);

      int qrow = qw + fg * 4;
#pragma unroll
      for (int r = 0; r < 4; ++r) { s0[r] *= 0.03125f; s1[r] *= 0.03125f; }
      if (kv0 + 31 > qw) {
#pragma unroll
        for (int r = 0; r < 4; ++r) {
          if (kv0 + fr > qrow + r) s0[r] = -1e30f;
          if (kv0 + 16 + fr > qrow + r) s1[r] = -1e30f;
        }
      }
      float tm[4], psum[4], alpha[4];
#pragma unroll
      for (int r = 0; r < 4; ++r) tm[r] = fmaxf(s0[r], s1[r]);
#pragma unroll
      for (int off = 1; off < 16; off <<= 1)
#pragma unroll
        for (int r = 0; r < 4; ++r) tm[r] = fmaxf(tm[r], __shfl_xor(tm[r], off));
#pragma unroll
      for (int r = 0; r < 4; ++r) {
        float mnew = fmaxf(mrow[r], tm[r]);
        alpha[r] = __expf(mrow[r] - mnew);
        mrow[r] = mnew;
        float p0 = __expf(s0[r] - mnew);
        float p1 = __expf(s1[r] - mnew);
        s0[r] = p0; s1[r] = p1;
        psum[r] = p0 + p1;
      }
#pragma unroll
      for (int off = 1; off < 16; off <<= 1)
#pragma unroll
        for (int r = 0; r < 4; ++r) psum[r] += __shfl_xor(psum[r], off);
#pragma unroll
      for (int r = 0; r < 4; ++r) lrow[r] = lrow[r] * alpha[r] + psum[r];
#pragma unroll
      for (int n = 0; n < 4; ++n)
#pragma unroll
        for (int r = 0; r < 4; ++r) acc_o[n][r] *= alpha[r];

#pragma unroll
      for (int r = 0; r < 4; ++r) {
        Ps[w][fg * 4 + r][fr] = (__bf16)s0[r];
        Ps[w][fg * 4 + r][16 + fr] = (__bf16)s1[r];
      }
      bf16x8 a_p = *(const bf16x8*)&Ps[w][fr][fg * 8];
#pragma unroll
      for (int n = 0; n < 4; ++n) {
        bf16x8 bvv;
#pragma unroll
        for (int j = 0; j < 8; ++j) bvv[j] = Vs[cur][fg * 8 + j][n * 16 + fr];
        acc_o[n] = __builtin_amdgcn_mfma_f32_16x16x32_bf16(a_p, bvv, acc_o[n], 0, 0, 0);
      }
    }
    __syncthreads();  // all reads of buf[cur^1] (iter t-1) and buf[cur] done
    if (t + 1 < ntile) {
      *(bf16x8*)&Ks[cur ^ 1][sr][sc] = k8n;
      *(bf16x4*)&Vs[cur ^ 1][sr][sc] = __builtin_shufflevector(v8n, v8n, 0, 1, 2, 3);
      *(bf16x4*)&Vs[cur ^ 1][sr][sc + 4] = __builtin_shufflevector(v8n, v8n, 4, 5, 6, 7);
    }
    __syncthreads();  // buf[cur^1] visible for iter t+1
  }
  float inv[4];
#pragma unroll
  for (int r = 0; r < 4; ++r) inv[r] = 1.0f / lrow[r];
  __bf16* ob = (__bf16*)o;
#pragma unroll
  for (int n = 0; n < 4; ++n)
#pragma unroll
    for (int r = 0; r < 4; ++r)
      ob[(bT + qw + fg * 4 + r) * 1024 + h * 64 + n * 16 + fr] = (__bf16)(acc_o[n][r] * inv[r]);
}

// ---------------------------------------------------------------- launch
extern "C" void kernel_launch(void* const* d_in, const int* in_sizes, int n_in,
                              void* d_out, int out_size, void* d_ws, size_t ws_size,
                              hipStream_t stream) {
  const int* idx = (const int*)d_in[0];
  const float* tok = (const float*)d_in[1];
  const float* pos = (const float*)d_in[2];
  const float* Wq = (const float*)d_in[3];
  const float* Wk = (const float*)d_in[4];
  const float* Wv = (const float*)d_in[5];
  const float* Phw = (const float*)d_in[6];
  const float* Phb = (const float*)d_in[7];
  const float* Pmw = (const float*)d_in[8];
  const float* Pmb = (const float*)d_in[9];
  const float* ln1g = (const float*)d_in[10];
  const float* ln1b = (const float*)d_in[11];
  const float* ln2g = (const float*)d_in[12];
  const float* ln2b = (const float*)d_in[13];
  const float* W1 = (const float*)d_in[14];
  const float* b1 = (const float*)d_in[15];
  const float* W2 = (const float*)d_in[16];
  const float* b2 = (const float*)d_in[17];
  const float* lnfg = (const float*)d_in[18];
  const float* lnfb = (const float*)d_in[19];
  const float* headw = (const float*)d_in[20];
  const float* headb = (const float*)d_in[21];
  float* out = (float*)d_out;

  // Workspace (~116 MB): x | bc | [qkvb ob hb = 64MB head-alias region] | xn | weights
  char* p = (char*)d_ws;
  float* x = (float*)p;                        p += (size_t)M * C * 4;
  float* bcv = (float*)p;                      p += 4096;
  char* layer_region = p;
  __hip_bfloat16* qkvb = (__hip_bfloat16*)p;   p += (size_t)M * 3072 * 2;
  __hip_bfloat16* ob = (__hip_bfloat16*)p;     p += (size_t)M * C * 2;
  __hip_bfloat16* hb = (__hip_bfloat16*)p;     p += (size_t)M * 4 * C * 2;
  __hip_bfloat16* xn = (__hip_bfloat16*)p;     p += (size_t)M * C * 2;
  __hip_bfloat16* qkvw = (__hip_bfloat16*)p;   p += (size_t)3 * C * C * 2;
  __hip_bfloat16* pmT = (__hip_bfloat16*)p;    p += (size_t)C * C * 2;
  __hip_bfloat16* phB = (__hip_bfloat16*)p;    p += (size_t)C * C * 2;
  __hip_bfloat16* wcombT = (__hip_bfloat16*)p; p += (size_t)C * C * 2;
  __hip_bfloat16* w1T = (__hip_bfloat16*)p;    p += (size_t)4 * C * C * 2;
  __hip_bfloat16* w2T = (__hip_bfloat16*)p;    p += (size_t)4 * C * C * 2;
  __hip_bfloat16* wt_head = (__hip_bfloat16*)layer_region;  // [V,C] bf16 = 64MB alias

  k_embed<<<(M * C / 4 + 255) / 256, 256, 0, stream>>>(idx, tok, pos, x);

  for (int l = 0; l < NL; ++l) {
    // ln1 -> xn (bf16)
    k_ln_bf<<<M, 256, 0, stream>>>(x, ln1g + (size_t)l * C, ln1b + (size_t)l * C, xn);
    // all weight prep in one launch
    k_prep<<<4096, 256, 0, stream>>>(Wq + (size_t)l * H * C * HS, Wk + (size_t)l * H * C * HS,
                                     Wv + (size_t)l * H * C * HS, Pmw + (size_t)l * C * C,
                                     Phw + (size_t)l * H * HS * C, W1 + (size_t)l * C * 4 * C,
                                     W2 + (size_t)l * 4 * C * C, qkvw, pmT, phB, w1T, w2T);
    // qkv = xn @ qkvw^T -> bf16 [M,3072]
    k_gemm256<0, 0, 0, 1><<<(3072 / 256) * (M / 256), 512, 0, stream>>>(xn, qkvw, qkvb, nullptr, nullptr, 3072, C);
    // attention -> ob (bf16)
    k_attn<<<dim3(T / 64, B * H), 256, 0, stream>>>(qkvb, ob);
    // combined bias + fused Ph*Pm weight
    k_biasc<<<16, 256, 0, stream>>>(Phb + (size_t)l * H * C, Pmw + (size_t)l * C * C, Pmb + (size_t)l * C, bcv);
    k_gemm_bf<0, 0, 0, 1><<<dim3(C / 128, C / 128), 256, 0, stream>>>(pmT, phB, wcombT, nullptr, nullptr, C, C);
    // x = x + ob @ wcombT^T + bc
    k_gemm_bf<1, 0, 1, 0><<<dim3(C / 128, M / 128), 256, 0, stream>>>(ob, wcombT, x, bcv, x, C, C);
    // ln2 -> xn
    k_ln_bf<<<M, 256, 0, stream>>>(x, ln2g + (size_t)l * C, ln2b + (size_t)l * C, xn);
    // h = gelu(xn @ W1 + b1)
    k_gemm256<1, 1, 0, 1><<<(4 * C / 256) * (M / 256), 512, 0, stream>>>(xn, w1T, hb, b1 + (size_t)l * 4 * C, nullptr, 4 * C, C);
    // x = x + h @ W2 + b2
    k_gemm_bf<1, 0, 1, 0><<<dim3(C / 128, M / 128), 256, 0, stream>>>(hb, w2T, x, b2 + (size_t)l * C, x, C, 4 * C);
  }

  // final LN + head
  k_ln_bf<<<M, 256, 0, stream>>>(x, lnfg, lnfb, xn);
  k_transp<<<dim3(500, 16), 256, 0, stream>>>(headw, wt_head, C, V);
  k_gemm256<1, 0, 0, 0><<<(V / 256) * (M / 256), 512, 0, stream>>>(xn, wt_head, out, headb, nullptr, V, C);
}

// Round 16
// 3572.834 us; speedup vs baseline: 1.0405x; 1.0136x over previous
//
#include <hip/hip_runtime.h>
#include <hip/hip_bf16.h>
#include <math.h>

static constexpr int V = 32000, B = 4, T = 1024, C = 1024, H = 16, NL = 8, HS = 64;
static constexpr int M = B * T; // 4096 rows of activations

typedef __bf16 bf16x8 __attribute__((ext_vector_type(8)));
typedef __bf16 bf16x4 __attribute__((ext_vector_type(4)));
typedef float f32x4 __attribute__((ext_vector_type(4)));

#define AS1 __attribute__((address_space(1)))
#define AS3 __attribute__((address_space(3)))

// ---------------------------------------------------------------- embed
__global__ void k_embed(const int* __restrict__ idx, const float* __restrict__ tok,
                        const float* __restrict__ pos, float* __restrict__ x) {
  int g = blockIdx.x * blockDim.x + threadIdx.x; // over M*C/4
  if (g >= M * C / 4) return;
  int c4 = g & 255;
  int bt = g >> 8;
  int t = bt & (T - 1);
  int row = idx[bt];
  float4 tv = *(const float4*)(tok + (size_t)row * C + c4 * 4);
  float4 pv = *(const float4*)(pos + (size_t)t * C + c4 * 4);
  float4 o;
  o.x = tv.x + pv.x; o.y = tv.y + pv.y; o.z = tv.z + pv.z; o.w = tv.w + pv.w;
  *(float4*)(x + (size_t)bt * C + c4 * 4) = o;
}

// ---------------------------------------------------------------- layernorm fp32 -> bf16
__global__ __launch_bounds__(256) void k_ln_bf(const float* __restrict__ x, const float* __restrict__ g,
                                               const float* __restrict__ b, __hip_bfloat16* __restrict__ y) {
  int row = blockIdx.x, tid = threadIdx.x;
  float4 v = ((const float4*)(x + (size_t)row * C))[tid];
  float s = v.x + v.y + v.z + v.w;
  float ss = v.x * v.x + v.y * v.y + v.z * v.z + v.w * v.w;
  for (int off = 32; off > 0; off >>= 1) {
    s += __shfl_down(s, off);
    ss += __shfl_down(ss, off);
  }
  __shared__ float sb[4], qb[4];
  int wid = tid >> 6;
  if ((tid & 63) == 0) { sb[wid] = s; qb[wid] = ss; }
  __syncthreads();
  float st = sb[0] + sb[1] + sb[2] + sb[3];
  float qt = qb[0] + qb[1] + qb[2] + qb[3];
  float mean = st * (1.0f / C);
  float var = qt * (1.0f / C) - mean * mean;
  float rstd = rsqrtf(var + 1e-5f);
  float4 gv = ((const float4*)g)[tid];
  float4 bv = ((const float4*)b)[tid];
  union { __hip_bfloat16 h[4]; ushort4 u; } pk;
  pk.h[0] = __float2bfloat16((v.x - mean) * rstd * gv.x + bv.x);
  pk.h[1] = __float2bfloat16((v.y - mean) * rstd * gv.y + bv.y);
  pk.h[2] = __float2bfloat16((v.z - mean) * rstd * gv.z + bv.z);
  pk.h[3] = __float2bfloat16((v.w - mean) * rstd * gv.w + bv.w);
  *(ushort4*)(y + (size_t)row * C + tid * 4) = pk.u;
}

// ---------------------------------------------------------------- transpose tile helper (device)
__device__ __forceinline__ void transp_block(const float* __restrict__ in, __hip_bfloat16* __restrict__ out,
                                             int K, int N, int bx, int by, float (*t)[65]) {
  int n0 = bx * 64, k0 = by * 64;
  int tx = threadIdx.x & 15, ty = threadIdx.x >> 4;
#pragma unroll
  for (int i = 0; i < 64; i += 16) {
    float4 v = *(const float4*)(in + (size_t)(k0 + ty + i) * N + n0 + tx * 4);
    t[ty + i][tx * 4 + 0] = v.x;
    t[ty + i][tx * 4 + 1] = v.y;
    t[ty + i][tx * 4 + 2] = v.z;
    t[ty + i][tx * 4 + 3] = v.w;
  }
  __syncthreads();
#pragma unroll
  for (int i = 0; i < 64; i += 16) {
    int n = ty + i;
    union { __hip_bfloat16 h[4]; ushort4 u; } pk;
#pragma unroll
    for (int j = 0; j < 4; ++j) pk.h[j] = __float2bfloat16(t[tx * 4 + j][n]);
    *(ushort4*)(out + (size_t)(n0 + n) * K + k0 + tx * 4) = pk.u;
  }
}

// ---------------------------------------------------------------- standalone transpose (head weight)
__global__ __launch_bounds__(256) void k_transp(const float* __restrict__ in, __hip_bfloat16* __restrict__ out,
                                                int K, int N) {
  __shared__ float t[64][65];
  transp_block(in, out, K, N, blockIdx.x, blockIdx.y, t);
}

// ---------------------------------------------------------------- merged per-layer weight prep
// bid 0..767: qkv pack; 768..1023: Pm^T; 1024..2047: Ph conv; 2048..3071: W1^T; 3072..4095: W2^T
__global__ __launch_bounds__(256) void k_prep(const float* __restrict__ Wq, const float* __restrict__ Wk,
                                              const float* __restrict__ Wv, const float* __restrict__ Pm,
                                              const float* __restrict__ Ph, const float* __restrict__ W1,
                                              const float* __restrict__ W2,
                                              __hip_bfloat16* __restrict__ qkvw, __hip_bfloat16* __restrict__ pmT,
                                              __hip_bfloat16* __restrict__ phB, __hip_bfloat16* __restrict__ w1T,
                                              __hip_bfloat16* __restrict__ w2T) {
  __shared__ float tls[64][65];
  int bid = blockIdx.x;
  if (bid < 768) {
    int bx = bid & 15, z = bid >> 4;
    int sel = z >> 4, h = z & 15;
    const float* W = sel == 0 ? Wq : (sel == 1 ? Wk : Wv);
    const float* in = W + (size_t)h * C * HS;
    __hip_bfloat16* o = qkvw + ((size_t)sel * 1024 + h * 64) * C;
    int k0 = bx * 64;
    int tx = threadIdx.x & 15, ty = threadIdx.x >> 4;
#pragma unroll
    for (int i = 0; i < 64; i += 16) {
      float4 v = *(const float4*)(in + (size_t)(k0 + ty + i) * HS + tx * 4);
      tls[ty + i][tx * 4 + 0] = v.x;
      tls[ty + i][tx * 4 + 1] = v.y;
      tls[ty + i][tx * 4 + 2] = v.z;
      tls[ty + i][tx * 4 + 3] = v.w;
    }
    __syncthreads();
#pragma unroll
    for (int i = 0; i < 64; i += 16) {
      int n = ty + i;
      union { __hip_bfloat16 h4[4]; ushort4 u; } pk;
#pragma unroll
      for (int j = 0; j < 4; ++j) pk.h4[j] = __float2bfloat16(tls[tx * 4 + j][n]);
      *(ushort4*)(o + (size_t)n * C + k0 + tx * 4) = pk.u;
    }
  } else if (bid < 1024) {
    int r = bid - 768;
    transp_block(Pm, pmT, C, C, r & 15, r >> 4, tls);
  } else if (bid < 2048) {
    int g = (bid - 1024) * 256 + threadIdx.x;  // over C*C/4
    float4 v = ((const float4*)Ph)[g];
    union { __hip_bfloat16 h[4]; ushort4 u; } pk;
    pk.h[0] = __float2bfloat16(v.x);
    pk.h[1] = __float2bfloat16(v.y);
    pk.h[2] = __float2bfloat16(v.z);
    pk.h[3] = __float2bfloat16(v.w);
    ((ushort4*)phB)[g] = pk.u;
  } else if (bid < 3072) {
    int r = bid - 2048;
    transp_block(W1, w1T, C, 4 * C, r & 63, r >> 6, tls);
  } else {
    int r = bid - 3072;
    transp_block(W2, w2T, 4 * C, C, r & 15, r >> 4, tls);
  }
}

// ---------------------------------------------------------------- merged bias: bc = (sum_h Phb[h]) @ Pm + Pm_b
__global__ __launch_bounds__(256) void k_biasc(const float* __restrict__ phb, const float* __restrict__ Pm,
                                               const float* __restrict__ Pmb, float* __restrict__ bc) {
  __shared__ float bs[1024];
  __shared__ float red[4][64];
  int tid = threadIdx.x;
#pragma unroll
  for (int q = 0; q < 4; ++q) {
    int c = tid * 4 + q;
    float s = 0.0f;
    for (int h = 0; h < H; ++h) s += phb[(size_t)h * C + c];
    bs[c] = s;
  }
  __syncthreads();
  int c = blockIdx.x * 64 + (tid & 63);
  int part = tid >> 6;
  float s = 0.0f;
  for (int j = part * 256; j < part * 256 + 256; ++j) s += bs[j] * Pm[(size_t)j * C + c];
  red[part][tid & 63] = s;
  __syncthreads();
  if (tid < 64)
    bc[blockIdx.x * 64 + tid] = Pmb[blockIdx.x * 64 + tid] + red[0][tid] + red[1][tid] + red[2][tid] + red[3][tid];
}

// ---------------------------------------------------------------- bf16 MFMA GEMM (m97 structure, 128x128, BK=32)
template <int BIAS, int GELU, int RES, int OUTBF>
__global__ __launch_bounds__(256) void k_gemm_bf(const __hip_bfloat16* __restrict__ A,
                                                 const __hip_bfloat16* __restrict__ Bt,
                                                 void* Cout, const float* __restrict__ bias,
                                                 const float* res, int N, int K) {
  __shared__ __align__(16) __hip_bfloat16 As[128 * 32];
  __shared__ __align__(16) __hip_bfloat16 Bs[128 * 32];
  int bm = blockIdx.y * 128, bn = blockIdx.x * 128;
  int tid = threadIdx.x;
  int w = tid >> 6, l = tid & 63;
  int wr = (w >> 1) * 64, wc = (w & 1) * 64;
  int lr = l >> 2;
  int lk = (l & 3) * 8;
  int fr = l & 15;
  int fk = (l >> 4) * 8;
  const __hip_bfloat16* Ag = A + (size_t)bm * K;
  const __hip_bfloat16* Bg = Bt + (size_t)bn * K;
  f32x4 acc[4][4];
#pragma unroll
  for (int m = 0; m < 4; ++m)
#pragma unroll
    for (int n = 0; n < 4; ++n) acc[m][n] = (f32x4){0.f, 0.f, 0.f, 0.f};

  for (int k0 = 0; k0 < K; k0 += 32) {
    __syncthreads();
#pragma unroll
    for (int i = 0; i < 2; ++i) {
      int seg = w * 2 + i;
      int r = seg * 16 + lr;
      __builtin_amdgcn_global_load_lds((const AS1 void*)(Ag + (size_t)r * K + k0 + lk),
                                       (AS3 void*)(As + seg * 512), 16, 0, 0);
      __builtin_amdgcn_global_load_lds((const AS1 void*)(Bg + (size_t)r * K + k0 + lk),
                                       (AS3 void*)(Bs + seg * 512), 16, 0, 0);
    }
    __syncthreads();
    bf16x8 af[4], bfr[4];
#pragma unroll
    for (int m = 0; m < 4; ++m) af[m] = *(const bf16x8*)(As + ((size_t)(wr + m * 16 + fr)) * 32 + fk);
#pragma unroll
    for (int n = 0; n < 4; ++n) bfr[n] = *(const bf16x8*)(Bs + ((size_t)(wc + n * 16 + fr)) * 32 + fk);
#pragma unroll
    for (int m = 0; m < 4; ++m)
#pragma unroll
      for (int n = 0; n < 4; ++n)
        acc[m][n] = __builtin_amdgcn_mfma_f32_16x16x32_bf16(af[m], bfr[n], acc[m][n], 0, 0, 0);
  }
  int crow0 = (l >> 4) * 4;
  int ccol = l & 15;
#pragma unroll
  for (int m = 0; m < 4; ++m) {
    int row = bm + wr + m * 16 + crow0;
#pragma unroll
    for (int n = 0; n < 4; ++n) {
      int col = bn + wc + n * 16 + ccol;
      float bv = BIAS ? bias[col] : 0.0f;
#pragma unroll
      for (int r = 0; r < 4; ++r) {
        float v = acc[m][n][r] + bv;
        if (GELU) v = 0.5f * v * (1.0f + erff(v * 0.70710678118f));
        if (RES) v += res[(size_t)(row + r) * N + col];
        if (OUTBF)
          ((__hip_bfloat16*)Cout)[(size_t)(row + r) * N + col] = __float2bfloat16(v);
        else
          ((float*)Cout)[(size_t)(row + r) * N + col] = v;
      }
    }
  }
}

// ---------------------------------------------------------------- 256x256 pipelined MFMA GEMM (8 waves, BK=32)
// R16 changes vs proven R13: (1) bm-fastest block mapping -- concurrent blocks on an
// XCD share ~2 B-panels (L2-resident) instead of 32 distinct panels, so B is fetched
// ~once per XCD instead of once per bm-row (head: B traffic ~470 MB -> ~64 MB);
// (2) fp32 (head) output uses nontemporal stores so the 512 MB write stream stops
// washing B out of L2/L3. Schedule/swizzle/vmcnt identical to R13.
// Requires M==4096 (16 m-tiles), N%256==0, K%64==0, nwg%8==0, NT=K/32 even >=4.
template <int BIAS, int GELU, int RES, int OUTBF>
__global__ __launch_bounds__(512, 2) void k_gemm256(const __hip_bfloat16* __restrict__ Ah,
                                                    const __hip_bfloat16* __restrict__ Bth,
                                                    void* Cout, const float* __restrict__ bias,
                                                    const float* res, int N, int K) {
  __shared__ __align__(16) __bf16 As[4][256 * 32];
  __shared__ __align__(16) __bf16 Bs[4][256 * 32];
  const __bf16* A = (const __bf16*)Ah;
  const __bf16* Bt = (const __bf16*)Bth;
  const int bid = blockIdx.x;
  const int sw = ((bid & 7) * ((int)gridDim.x >> 3)) + (bid >> 3);  // XCD-chunk swizzle
  const int bm = (sw & 15) << 8;   // m-tile fastest (16 m-tiles, M=4096)
  const int bn = (sw >> 4) << 8;
  const int tid = threadIdx.x, w = tid >> 6, l = tid & 63;
  const int wm = w >> 2, wn = w & 3;
  const int fr = l & 15, fg = l >> 4;
  const int srow = w * 32 + (l >> 2);  // + jj*16
  const int scole = ((((l & 3) << 4) ^ ((l & 8) << 2) ^ (l & 16)) >> 1);
  const __bf16* Ag = A + (size_t)(bm + srow) * K + scole;
  const __bf16* Bg = Bt + (size_t)(bn + srow) * K + scole;
  const int arow = wm * 128 + fr;  // + mg*16
  const int brow = wn * 64 + fr;   // + ng*16
  const int koff = (((fg * 16) ^ (((fr & 2) << 4) | ((fr & 4) << 2))) >> 1);  // elements

  f32x4 acc[8][4];
#pragma unroll
  for (int m = 0; m < 8; ++m)
#pragma unroll
    for (int n = 0; n < 4; ++n) acc[m][n] = (f32x4){0.f, 0.f, 0.f, 0.f};

  auto stage = [&](int bufi, int tt) {
    size_t kb = (size_t)tt * 32;
#pragma unroll
    for (int jj = 0; jj < 2; ++jj) {
      __builtin_amdgcn_global_load_lds((const AS1 void*)(Ag + (size_t)jj * 16 * K + kb),
                                       (AS3 void*)(&As[bufi][(w * 32 + jj * 16) * 32]), 16, 0, 0);
      __builtin_amdgcn_global_load_lds((const AS1 void*)(Bg + (size_t)jj * 16 * K + kb),
                                       (AS3 void*)(&Bs[bufi][(w * 32 + jj * 16) * 32]), 16, 0, 0);
    }
  };

  bf16x8 fa[2][8], fb[2][4];

#define READF(SET, BI)                                                              \
  {                                                                                 \
    const int bi_ = (BI);                                                           \
    _Pragma("unroll") for (int mg = 0; mg < 8; ++mg)                                \
        fa[SET][mg] = *(const bf16x8*)(&As[bi_][(arow + mg * 16) * 32 + koff]);     \
    _Pragma("unroll") for (int ng = 0; ng < 4; ++ng)                                \
        fb[SET][ng] = *(const bf16x8*)(&Bs[bi_][(brow + ng * 16) * 32 + koff]);     \
  }

#define MFMAS(SET)                                                                  \
  _Pragma("unroll") for (int mg = 0; mg < 8; ++mg)                                  \
      _Pragma("unroll") for (int ng = 0; ng < 4; ++ng)                              \
          acc[mg][ng] =                                                             \
              __builtin_amdgcn_mfma_f32_16x16x32_bf16(fa[SET][mg], fb[SET][ng], acc[mg][ng], 0, 0, 0);

#define GITER(T, CUR, NXT)                                                          \
  {                                                                                 \
    const int t_ = (T);                                                             \
    asm volatile("s_waitcnt lgkmcnt(0)" ::: "memory");                              \
    if (t_ + 2 < NT)                                                                \
      asm volatile("s_waitcnt vmcnt(4)" ::: "memory");                              \
    else                                                                            \
      asm volatile("s_waitcnt vmcnt(0)" ::: "memory");                              \
    __builtin_amdgcn_sched_barrier(0);                                              \
    __builtin_amdgcn_s_barrier();                                                   \
    __builtin_amdgcn_sched_barrier(0);                                              \
    if (t_ + 1 < NT) READF(NXT, (t_ + 1) & 3);                                      \
    if (t_ + 3 < NT) stage((t_ + 3) & 3, t_ + 3);                                   \
    __builtin_amdgcn_s_setprio(1);                                                  \
    MFMAS(CUR);                                                                     \
    __builtin_amdgcn_s_setprio(0);                                                  \
  }

  const int NT = K >> 5;
  stage(0, 0);
  stage(1, 1);
  stage(2, 2);
  asm volatile("s_waitcnt vmcnt(8)" ::: "memory");
  __builtin_amdgcn_sched_barrier(0);
  __builtin_amdgcn_s_barrier();
  __builtin_amdgcn_sched_barrier(0);
  READF(0, 0);

  for (int t = 0; t < NT; t += 2) {
    GITER(t, 0, 1);
    GITER(t + 1, 1, 0);
  }
#undef READF
#undef MFMAS
#undef GITER

#pragma unroll
  for (int mg = 0; mg < 8; ++mg) {
    int row = bm + wm * 128 + mg * 16 + fg * 4;
#pragma unroll
    for (int n = 0; n < 4; ++n) {
      int col = bn + wn * 64 + n * 16 + fr;
      float bvx = BIAS ? bias[col] : 0.0f;
#pragma unroll
      for (int r = 0; r < 4; ++r) {
        float v = acc[mg][n][r] + bvx;
        if (GELU) v = 0.5f * v * (1.0f + erff(v * 0.70710678118f));
        if (RES) v += res[(size_t)(row + r) * N + col];
        if (OUTBF)
          ((__hip_bfloat16*)Cout)[(size_t)(row + r) * N + col] = __float2bfloat16(v);
        else
          __builtin_nontemporal_store(v, &((float*)Cout)[(size_t)(row + r) * N + col]);
      }
    }
  }
}

// ---------------------------------------------------------------- MFMA flash attention (proven R13 version)
__global__ __launch_bounds__(256) void k_attn(const __hip_bfloat16* __restrict__ qkvh,
                                              __hip_bfloat16* __restrict__ o) {
  const __bf16* qkv = (const __bf16*)qkvh;
  int qi = blockIdx.x;
  int bh = blockIdx.y;
  int b = bh >> 4, h = bh & 15;
  int tid = threadIdx.x;
  int w = tid >> 6, l = tid & 63;
  int fr = l & 15, fg = l >> 4;
  int qw = qi * 64 + w * 16;

  __shared__ __align__(16) __bf16 Ks[32][72];
  __shared__ __align__(16) __bf16 Vs[32][76];
  __shared__ __align__(16) __bf16 Ps[4][16][40];

  const size_t bT = (size_t)b * T;
  bf16x8 a_q[2];
  {
    const __bf16* qp = qkv + (bT + qw + fr) * 3072 + h * 64 + fg * 8;
    a_q[0] = *(const bf16x8*)qp;
    a_q[1] = *(const bf16x8*)(qp + 32);
  }
  f32x4 acc_o[4];
#pragma unroll
  for (int n = 0; n < 4; ++n) acc_o[n] = (f32x4){0.f, 0.f, 0.f, 0.f};
  float mrow[4] = {-1e30f, -1e30f, -1e30f, -1e30f};
  float lrow[4] = {0.f, 0.f, 0.f, 0.f};

  int sr = tid >> 3;
  int sc = (tid & 7) * 8;
  int ntile = (qi + 1) * 2;
  for (int t = 0; t < ntile; ++t) {
    int kv0 = t * 32;
    __syncthreads();
    {
      const __bf16* kp = qkv + (bT + kv0 + sr) * 3072 + 1024 + h * 64 + sc;
      bf16x8 k8 = *(const bf16x8*)kp;
      bf16x8 v8 = *(const bf16x8*)(kp + 1024);
      *(bf16x8*)&Ks[sr][sc] = k8;
      *(bf16x4*)&Vs[sr][sc] = __builtin_shufflevector(v8, v8, 0, 1, 2, 3);
      *(bf16x4*)&Vs[sr][sc + 4] = __builtin_shufflevector(v8, v8, 4, 5, 6, 7);
    }
    __syncthreads();
    if (kv0 > qw + 15) continue;

    f32x4 s0 = (f32x4){0.f, 0.f, 0.f, 0.f}, s1 = s0;
    s0 = __builtin_amdgcn_mfma_f32_16x16x32_bf16(a_q[0], *(const bf16x8*)&Ks[fr][fg * 8], s0, 0, 0, 0);
    s0 = __builtin_amdgcn_mfma_f32_16x16x32_bf16(a_q[1], *(const bf16x8*)&Ks[fr][32 + fg * 8], s0, 0, 0, 0);
    s1 = __builtin_amdgcn_mfma_f32_16x16x32_bf16(a_q[0], *(const bf16x8*)&Ks[16 + fr][fg * 8], s1, 0, 0, 0);
    s1 = __builtin_amdgcn_mfma_f32_16x16x32_bf16(a_q[1], *(const bf16x8*)&Ks[16 + fr][32 + fg * 8], s1, 0, 0, 0);

    int qrow = qw + fg * 4;
#pragma unroll
    for (int r = 0; r < 4; ++r) { s0[r] *= 0.03125f; s1[r] *= 0.03125f; }
    if (kv0 + 31 > qw) {
#pragma unroll
      for (int r = 0; r < 4; ++r) {
        if (kv0 + fr > qrow + r) s0[r] = -1e30f;
        if (kv0 + 16 + fr > qrow + r) s1[r] = -1e30f;
      }
    }
    float tm[4], psum[4], alpha[4];
#pragma unroll
    for (int r = 0; r < 4; ++r) tm[r] = fmaxf(s0[r], s1[r]);
#pragma unroll
    for (int off = 1; off < 16; off <<= 1)
#pragma unroll
      for (int r = 0; r < 4; ++r) tm[r] = fmaxf(tm[r], __shfl_xor(tm[r], off));
#pragma unroll
    for (int r = 0; r < 4; ++r) {
      float mnew = fmaxf(mrow[r], tm[r]);
      alpha[r] = __expf(mrow[r] - mnew);
      mrow[r] = mnew;
      float p0 = __expf(s0[r] - mnew);
      float p1 = __expf(s1[r] - mnew);
      s0[r] = p0; s1[r] = p1;
      psum[r] = p0 + p1;
    }
#pragma unroll
    for (int off = 1; off < 16; off <<= 1)
#pragma unroll
      for (int r = 0; r < 4; ++r) psum[r] += __shfl_xor(psum[r], off);
#pragma unroll
    for (int r = 0; r < 4; ++r) lrow[r] = lrow[r] * alpha[r] + psum[r];
#pragma unroll
    for (int n = 0; n < 4; ++n)
#pragma unroll
      for (int r = 0; r < 4; ++r) acc_o[n][r] *= alpha[r];

#pragma unroll
    for (int r = 0; r < 4; ++r) {
      Ps[w][fg * 4 + r][fr] = (__bf16)s0[r];
      Ps[w][fg * 4 + r][16 + fr] = (__bf16)s1[r];
    }
    bf16x8 a_p = *(const bf16x8*)&Ps[w][fr][fg * 8];
#pragma unroll
    for (int n = 0; n < 4; ++n) {
      bf16x8 bvv;
#pragma unroll
      for (int j = 0; j < 8; ++j) bvv[j] = Vs[fg * 8 + j][n * 16 + fr];
      acc_o[n] = __builtin_amdgcn_mfma_f32_16x16x32_bf16(a_p, bvv, acc_o[n], 0, 0, 0);
    }
  }
  float inv[4];
#pragma unroll
  for (int r = 0; r < 4; ++r) inv[r] = 1.0f / lrow[r];
  __bf16* ob = (__bf16*)o;
#pragma unroll
  for (int n = 0; n < 4; ++n)
#pragma unroll
    for (int r = 0; r < 4; ++r)
      ob[(bT + qw + fg * 4 + r) * 1024 + h * 64 + n * 16 + fr] = (__bf16)(acc_o[n][r] * inv[r]);
}

// ---------------------------------------------------------------- launch
extern "C" void kernel_launch(void* const* d_in, const int* in_sizes, int n_in,
                              void* d_out, int out_size, void* d_ws, size_t ws_size,
                              hipStream_t stream) {
  const int* idx = (const int*)d_in[0];
  const float* tok = (const float*)d_in[1];
  const float* pos = (const float*)d_in[2];
  const float* Wq = (const float*)d_in[3];
  const float* Wk = (const float*)d_in[4];
  const float* Wv = (const float*)d_in[5];
  const float* Phw = (const float*)d_in[6];
  const float* Phb = (const float*)d_in[7];
  const float* Pmw = (const float*)d_in[8];
  const float* Pmb = (const float*)d_in[9];
  const float* ln1g = (const float*)d_in[10];
  const float* ln1b = (const float*)d_in[11];
  const float* ln2g = (const float*)d_in[12];
  const float* ln2b = (const float*)d_in[13];
  const float* W1 = (const float*)d_in[14];
  const float* b1 = (const float*)d_in[15];
  const float* W2 = (const float*)d_in[16];
  const float* b2 = (const float*)d_in[17];
  const float* lnfg = (const float*)d_in[18];
  const float* lnfb = (const float*)d_in[19];
  const float* headw = (const float*)d_in[20];
  const float* headb = (const float*)d_in[21];
  float* out = (float*)d_out;

  // Workspace (~116 MB): x | bc | [qkvb ob hb = 64MB head-alias region] | xn | weights
  char* p = (char*)d_ws;
  float* x = (float*)p;                        p += (size_t)M * C * 4;
  float* bcv = (float*)p;                      p += 4096;
  char* layer_region = p;
  __hip_bfloat16* qkvb = (__hip_bfloat16*)p;   p += (size_t)M * 3072 * 2;
  __hip_bfloat16* ob = (__hip_bfloat16*)p;     p += (size_t)M * C * 2;
  __hip_bfloat16* hb = (__hip_bfloat16*)p;     p += (size_t)M * 4 * C * 2;
  __hip_bfloat16* xn = (__hip_bfloat16*)p;     p += (size_t)M * C * 2;
  __hip_bfloat16* qkvw = (__hip_bfloat16*)p;   p += (size_t)3 * C * C * 2;
  __hip_bfloat16* pmT = (__hip_bfloat16*)p;    p += (size_t)C * C * 2;
  __hip_bfloat16* phB = (__hip_bfloat16*)p;    p += (size_t)C * C * 2;
  __hip_bfloat16* wcombT = (__hip_bfloat16*)p; p += (size_t)C * C * 2;
  __hip_bfloat16* w1T = (__hip_bfloat16*)p;    p += (size_t)4 * C * C * 2;
  __hip_bfloat16* w2T = (__hip_bfloat16*)p;    p += (size_t)4 * C * C * 2;
  __hip_bfloat16* wt_head = (__hip_bfloat16*)layer_region;  // [V,C] bf16 = 64MB alias

  k_embed<<<(M * C / 4 + 255) / 256, 256, 0, stream>>>(idx, tok, pos, x);

  for (int l = 0; l < NL; ++l) {
    // ln1 -> xn (bf16)
    k_ln_bf<<<M, 256, 0, stream>>>(x, ln1g + (size_t)l * C, ln1b + (size_t)l * C, xn);
    // all weight prep in one launch
    k_prep<<<4096, 256, 0, stream>>>(Wq + (size_t)l * H * C * HS, Wk + (size_t)l * H * C * HS,
                                     Wv + (size_t)l * H * C * HS, Pmw + (size_t)l * C * C,
                                     Phw + (size_t)l * H * HS * C, W1 + (size_t)l * C * 4 * C,
                                     W2 + (size_t)l * 4 * C * C, qkvw, pmT, phB, w1T, w2T);
    // qkv = xn @ qkvw^T -> bf16 [M,3072]
    k_gemm256<0, 0, 0, 1><<<(3072 / 256) * (M / 256), 512, 0, stream>>>(xn, qkvw, qkvb, nullptr, nullptr, 3072, C);
    // attention -> ob (bf16)
    k_attn<<<dim3(T / 64, B * H), 256, 0, stream>>>(qkvb, ob);
    // combined bias + fused Ph*Pm weight
    k_biasc<<<16, 256, 0, stream>>>(Phb + (size_t)l * H * C, Pmw + (size_t)l * C * C, Pmb + (size_t)l * C, bcv);
    k_gemm_bf<0, 0, 0, 1><<<dim3(C / 128, C / 128), 256, 0, stream>>>(pmT, phB, wcombT, nullptr, nullptr, C, C);
    // x = x + ob @ wcombT^T + bc
    k_gemm_bf<1, 0, 1, 0><<<dim3(C / 128, M / 128), 256, 0, stream>>>(ob, wcombT, x, bcv, x, C, C);
    // ln2 -> xn
    k_ln_bf<<<M, 256, 0, stream>>>(x, ln2g + (size_t)l * C, ln2b + (size_t)l * C, xn);
    // h = gelu(xn @ W1 + b1)
    k_gemm256<1, 1, 0, 1><<<(4 * C / 256) * (M / 256), 512, 0, stream>>>(xn, w1T, hb, b1 + (size_t)l * 4 * C, nullptr, 4 * C, C);
    // x = x + h @ W2 + b2
    k_gemm_bf<1, 0, 1, 0><<<dim3(C / 128, M / 128), 256, 0, stream>>>(hb, w2T, x, b2 + (size_t)l * C, x, C, 4 * C);
  }

  // final LN + head
  k_ln_bf<<<M, 256, 0, stream>>>(x, lnfg, lnfb, xn);
  k_transp<<<dim3(500, 16), 256, 0, stream>>>(headw, wt_head, C, V);
  k_gemm256<1, 0, 0, 0><<<(V / 256) * (M / 256), 512, 0, stream>>>(xn, wt_head, out, headb, nullptr, V, C);
}